// Round 1
// baseline (2815.197 us; speedup 1.0000x reference)
//
#include <hip/hip_runtime.h>

// Kuramoto helix network, fully fused persistent kernel (f32 baseline).
// Batch rows are independent -> one kernel, block owns 8 rows, loops all
// 4 layers x 10 steps locally. K (256KB/layer) streamed from L2 each step.

#define N_BATCH 2048
#define N_IN    512
#define N_OUT   128
#define NOSC    256
#define NLAYERS 4
#define NSTEPS  10

__device__ __forceinline__ float wrapf(float t) {
    // == atan2f(sinf(t), cosf(t)) for |t| < ~pi + 0.6 (our range), up to ulp
    return t - 6.28318530717958648f * rintf(t * 0.159154943091895336f);
}

__device__ __forceinline__ float dot4(float4 a, float4 b) {
    return a.x * b.x + a.y * b.y + a.z * b.z + a.w * b.w;
}

__global__ __launch_bounds__(512) void helix_all(
    const float* __restrict__ x,
    const float* __restrict__ W_enc,
    const float* __restrict__ b_enc,
    const float* __restrict__ Ks,
    const float* __restrict__ omegas,
    const float* __restrict__ Kgl,
    const float* __restrict__ mgl,
    const float* __restrict__ W_dec,
    const float* __restrict__ b_dec,
    float* __restrict__ out)
{
    // sm: encoder phase = X[8][512]; dynamics phase = S[8][256] | C[8][256]
    __shared__ float sm[4096];
    float* Ssh = sm;
    float* Csh = sm + 2048;

    const int t    = threadIdx.x;       // 0..511
    const int r    = t >> 6;            // row within block, 0..7 (one wave per row)
    const int ig   = t & 63;            // lane
    const int i0   = ig << 2;           // this thread owns oscillators i0..i0+3
    const int row0 = blockIdx.x * 8;
    const int row  = row0 + r;

    float* out_y   = out;                         // [2048][128]
    float* out_th  = out + N_BATCH * N_OUT;       // [2048][256]
    float* out_coh = out + N_BATCH * (N_OUT + NOSC); // [2048]

    // ---- stage this block's 8 input rows into LDS ----
    {
        const float4* xg = (const float4*)(x + (size_t)row0 * N_IN);
        float4* xs = (float4*)sm;
        xs[t]       = xg[t];
        xs[t + 512] = xg[t + 512];
    }
    __syncthreads();

    // ---- encoder: th[m] = wrap( x[row] . W_enc[i0+m] + b_enc ) ----
    float th[4];
    {
        float a0 = 0.f, a1 = 0.f, a2 = 0.f, a3 = 0.f;
        const float4* Xr  = (const float4*)(sm + r * N_IN);
        const float4* w0p = (const float4*)(W_enc + (size_t)(i0 + 0) * N_IN);
        const float4* w1p = (const float4*)(W_enc + (size_t)(i0 + 1) * N_IN);
        const float4* w2p = (const float4*)(W_enc + (size_t)(i0 + 2) * N_IN);
        const float4* w3p = (const float4*)(W_enc + (size_t)(i0 + 3) * N_IN);
        #pragma unroll 4
        for (int k4 = 0; k4 < N_IN / 4; ++k4) {
            float4 x4 = Xr[k4];
            a0 += dot4(w0p[k4], x4);
            a1 += dot4(w1p[k4], x4);
            a2 += dot4(w2p[k4], x4);
            a3 += dot4(w3p[k4], x4);
        }
        th[0] = wrapf(a0 + b_enc[i0 + 0]);
        th[1] = wrapf(a1 + b_enc[i0 + 1]);
        th[2] = wrapf(a2 + b_enc[i0 + 2]);
        th[3] = wrapf(a3 + b_enc[i0 + 3]);
    }

    // ---- 4 layers x 10 Kuramoto steps ----
    for (int l = 0; l < NLAYERS; ++l) {
        const float* Kp = Ks + (size_t)l * NOSC * NOSC;
        const float4 omg = ((const float4*)(omegas + l * NOSC))[ig];
        // fold K_eff scale (mu_gate*0.5) and K_global/N into one coefficient
        const float cc = Kgl[l] * (1.0f / (float)NOSC) * (mgl[l] * 0.5f);

        const float4* k0p = (const float4*)(Kp + (size_t)(i0 + 0) * NOSC);
        const float4* k1p = (const float4*)(Kp + (size_t)(i0 + 1) * NOSC);
        const float4* k2p = (const float4*)(Kp + (size_t)(i0 + 2) * NOSC);
        const float4* k3p = (const float4*)(Kp + (size_t)(i0 + 3) * NOSC);

        for (int st = 0; st < NSTEPS; ++st) {
            float sv[4], cv[4];
            #pragma unroll
            for (int m = 0; m < 4; ++m) sincosf(th[m], &sv[m], &cv[m]);

            __syncthreads();  // all readers of S/C (prev step / encoder X) done
            *((float4*)(Ssh + r * NOSC + i0)) = make_float4(sv[0], sv[1], sv[2], sv[3]);
            *((float4*)(Csh + r * NOSC + i0)) = make_float4(cv[0], cv[1], cv[2], cv[3]);
            __syncthreads();  // S/C fully written

            float aS0 = 0.f, aS1 = 0.f, aS2 = 0.f, aS3 = 0.f;
            float aC0 = 0.f, aC1 = 0.f, aC2 = 0.f, aC3 = 0.f;
            const float4* Sr = (const float4*)(Ssh + r * NOSC);
            const float4* Cr = (const float4*)(Csh + r * NOSC);
            #pragma unroll 4
            for (int j4 = 0; j4 < NOSC / 4; ++j4) {
                float4 s4 = Sr[j4];
                float4 c4 = Cr[j4];
                float4 k;
                k = k0p[j4]; aS0 += dot4(k, s4); aC0 += dot4(k, c4);
                k = k1p[j4]; aS1 += dot4(k, s4); aC1 += dot4(k, c4);
                k = k2p[j4]; aS2 += dot4(k, s4); aC2 += dot4(k, c4);
                k = k3p[j4]; aS3 += dot4(k, s4); aC3 += dot4(k, c4);
            }
            // dtheta = omega + (Kg/N) * mu*0.5 * (c*(K s) - s*(K c)); th = wrap(th + dt*dtheta)
            th[0] = wrapf(th[0] + 0.1f * (omg.x + cc * (cv[0] * aS0 - sv[0] * aC0)));
            th[1] = wrapf(th[1] + 0.1f * (omg.y + cc * (cv[1] * aS1 - sv[1] * aC1)));
            th[2] = wrapf(th[2] + 0.1f * (omg.z + cc * (cv[2] * aS2 - sv[2] * aC2)));
            th[3] = wrapf(th[3] + 0.1f * (omg.w + cc * (cv[3] * aS3 - sv[3] * aC3)));
        }
    }

    // ---- epilogue ----
    // 1. theta out (coalesced float4)
    const float4 th4 = make_float4(th[0], th[1], th[2], th[3]);
    *((float4*)(out_th + (size_t)row * NOSC + i0)) = th4;

    // 2. coherence: one wave == one row, shuffle-reduce over 64 lanes
    {
        float ls = 0.f, lc = 0.f;
        #pragma unroll
        for (int m = 0; m < 4; ++m) {
            float ss, cs;
            sincosf(th[m], &ss, &cs);
            ls += ss; lc += cs;
        }
        #pragma unroll
        for (int off = 32; off > 0; off >>= 1) {
            ls += __shfl_xor(ls, off);
            lc += __shfl_xor(lc, off);
        }
        if (ig == 0) {
            float ms = ls * (1.0f / (float)NOSC);
            float mc = lc * (1.0f / (float)NOSC);
            out_coh[row] = sqrtf(ms * ms + mc * mc);
        }
    }

    // 3. decoder: stage final theta in LDS, each thread computes 2 outputs
    __syncthreads();  // everyone done reading S/C from last GEMM
    *((float4*)(Ssh + r * NOSC + i0)) = th4;
    __syncthreads();
    {
        const int o0 = ig << 1;
        float a0 = b_dec[o0], a1 = b_dec[o0 + 1];
        const float4* Tr  = (const float4*)(Ssh + r * NOSC);
        const float4* wd0 = (const float4*)(W_dec + (size_t)o0 * NOSC);
        const float4* wd1 = (const float4*)(W_dec + (size_t)(o0 + 1) * NOSC);
        #pragma unroll 4
        for (int i4 = 0; i4 < NOSC / 4; ++i4) {
            float4 t4 = Tr[i4];
            a0 += dot4(wd0[i4], t4);
            a1 += dot4(wd1[i4], t4);
        }
        *((float2*)(out_y + (size_t)row * N_OUT + o0)) = make_float2(a0, a1);
    }
}

extern "C" void kernel_launch(void* const* d_in, const int* in_sizes, int n_in,
                              void* d_out, int out_size, void* d_ws, size_t ws_size,
                              hipStream_t stream) {
    helix_all<<<N_BATCH / 8, 512, 0, stream>>>(
        (const float*)d_in[0],  // x
        (const float*)d_in[1],  // W_enc
        (const float*)d_in[2],  // b_enc
        (const float*)d_in[3],  // Ks
        (const float*)d_in[4],  // omegas
        (const float*)d_in[5],  // K_globals
        (const float*)d_in[6],  // mu_gates
        (const float*)d_in[7],  // W_dec
        (const float*)d_in[8],  // b_dec
        (float*)d_out);
}

// Round 2
// 189.461 us; speedup vs baseline: 14.8590x; 14.8590x over previous
//
#include <hip/hip_runtime.h>

// Kuramoto helix network, fused persistent kernel.
// Dynamics coupling GEMMs on MFMA f16 (K cached in registers as B-frags),
// theta state f32 in registers, S/C exchanged via double-buffered swizzled LDS.
// Block = 512 threads (8 waves) owns 16 batch rows; wave w owns oscillator
// cols [32w, 32w+32). Grid = 2048/16 = 128.

#define NB    2048
#define NIN   512
#define NOUT  128
#define NOSC  256
#define NL    4
#define NST   10
#define ROWS  16
#define DTT   0.1f

typedef _Float16 f16;
typedef _Float16 f16x8 __attribute__((ext_vector_type(8)));
typedef float f32x4 __attribute__((ext_vector_type(4)));

__device__ __forceinline__ float wrapf(float t) {
    // == atan2f(sinf(t), cosf(t)) for |t| < ~pi + 0.6 (our range)
    return t - 6.28318530717958648f * rintf(t * 0.159154943091895336f);
}

__device__ __forceinline__ float dot4(float4 a, float4 b) {
    return a.x * b.x + a.y * b.y + a.z * b.z + a.w * b.w;
}

__global__ __launch_bounds__(512) void helix_mfma(
    const float* __restrict__ x,
    const float* __restrict__ W_enc,
    const float* __restrict__ b_enc,
    const float* __restrict__ Ks,
    const float* __restrict__ omegas,
    const float* __restrict__ Kgl,
    const float* __restrict__ mgl,
    const float* __restrict__ W_dec,
    const float* __restrict__ b_dec,
    float* __restrict__ out)
{
    // Encoder phase: xs[16][516] f32 (padded rows: 4-dword row offset kills
    // 4-way broadcast-read conflicts). Dynamics phase: same bytes become
    // S/C f16 double buffer: [buf2][S|C][row16][512B], 32KB.
    __shared__ float xs[ROWS * 516];            // 33024 B
    __shared__ float th_lds[ROWS * NOSC];       // 16 KB, final theta for decoder
    __shared__ float cohS[ROWS], cohC[ROWS];

    char* scbase = (char*)xs;

    const int tid  = threadIdx.x;
    const int w    = tid >> 6;      // wave 0..7
    const int ln   = tid & 63;
    const int lr   = ln & 15;       // fragment row/col lane
    const int lg   = ln >> 4;       // 0..3
    const int row0 = blockIdx.x * ROWS;
    // D-layout ownership: b(m) = lg*4 + m (batch row in block), i(t) = 32w + 16t + lr
    const int iA = 32 * w + lr;         // t = 0 oscillator col
    const int iB = iA + 16;             // t = 1 oscillator col

    float* out_y   = out;                          // [2048][128]
    float* out_th  = out + (size_t)NB * NOUT;      // [2048][256]
    float* out_coh = out + (size_t)NB * (NOUT + NOSC); // [2048]

    if (tid < ROWS) { cohS[tid] = 0.f; cohC[tid] = 0.f; }

    // ---- stage x rows into LDS (padded rows) ----
    {
        const float4* xg = (const float4*)(x + (size_t)row0 * NIN);
        #pragma unroll
        for (int q = 0; q < 4; ++q) {
            int idx = tid + q * 512;          // float4 index, 2048 total
            int r   = idx >> 7;               // row (128 float4/row)
            int c   = idx & 127;
            *(float4*)&xs[r * 516 + c * 4] = xg[idx];
        }
    }
    __syncthreads();

    // ---- encoder: th[t][m] = wrap( x[b(m)] . W_enc[i(t)] ), f32 vector ----
    float th[2][4];
    {
        float acc[2][4] = {{0.f,0.f,0.f,0.f},{0.f,0.f,0.f,0.f}};
        const float4* wp0 = (const float4*)(W_enc + (size_t)iA * NIN);
        const float4* wp1 = (const float4*)(W_enc + (size_t)iB * NIN);
        #pragma unroll 4
        for (int k = 0; k < 128; ++k) {
            float4 w0 = wp0[k];
            float4 w1 = wp1[k];
            #pragma unroll
            for (int m = 0; m < 4; ++m) {
                float4 xv = *(const float4*)&xs[(lg * 4 + m) * 516 + k * 4];
                acc[0][m] += dot4(w0, xv);
                acc[1][m] += dot4(w1, xv);
            }
        }
        #pragma unroll
        for (int m = 0; m < 4; ++m) {
            th[0][m] = wrapf(acc[0][m] + b_enc[iA]);
            th[1][m] = wrapf(acc[1][m] + b_enc[iB]);
        }
    }
    __syncthreads();  // xs reads done before S/C overwrite

    // ---- dynamics: 4 layers x 10 steps, MFMA f16 ----
    int step = 0;
    for (int l = 0; l < NL; ++l) {
        // B-frags: B[k=j][n=i] = K[i][j]; lane lr = col i, lg*8.. = j-slice.
        f16x8 Bf[2][8];
        {
            const float* KpA = Ks + (size_t)l * NOSC * NOSC + (size_t)iA * NOSC;
            const float* KpB = Ks + (size_t)l * NOSC * NOSC + (size_t)iB * NOSC;
            #pragma unroll
            for (int k = 0; k < 8; ++k) {
                const int j0 = k * 32 + lg * 8;
                float4 a0 = *(const float4*)(KpA + j0);
                float4 a1 = *(const float4*)(KpA + j0 + 4);
                float4 b0 = *(const float4*)(KpB + j0);
                float4 b1 = *(const float4*)(KpB + j0 + 4);
                f16x8 fA, fB;
                fA[0]=(f16)a0.x; fA[1]=(f16)a0.y; fA[2]=(f16)a0.z; fA[3]=(f16)a0.w;
                fA[4]=(f16)a1.x; fA[5]=(f16)a1.y; fA[6]=(f16)a1.z; fA[7]=(f16)a1.w;
                fB[0]=(f16)b0.x; fB[1]=(f16)b0.y; fB[2]=(f16)b0.z; fB[3]=(f16)b0.w;
                fB[4]=(f16)b1.x; fB[5]=(f16)b1.y; fB[6]=(f16)b1.z; fB[7]=(f16)b1.w;
                Bf[0][k] = fA;
                Bf[1][k] = fB;
            }
        }
        const float om0 = omegas[l * NOSC + iA];
        const float om1 = omegas[l * NOSC + iB];
        const float cc  = Kgl[l] * (1.0f / (float)NOSC) * (mgl[l] * 0.5f);

        for (int st = 0; st < NST; ++st, ++step) {
            float sv[2][4], cv[2][4];
            #pragma unroll
            for (int t = 0; t < 2; ++t)
                #pragma unroll
                for (int m = 0; m < 4; ++m)
                    __sincosf(th[t][m], &sv[t][m], &cv[t][m]);

            char* Sb = scbase + (step & 1) * 16384;
            char* Cb = Sb + 8192;

            // write phase (before the single barrier; dbuf makes WAR safe)
            #pragma unroll
            for (int t = 0; t < 2; ++t) {
                const int i = (t == 0) ? iA : iB;
                #pragma unroll
                for (int m = 0; m < 4; ++m) {
                    const int b   = lg * 4 + m;
                    const int off = b * 512 + ((i * 2) ^ ((b & 7) << 4));
                    *(f16*)(Sb + off) = (f16)sv[t][m];
                    *(f16*)(Cb + off) = (f16)cv[t][m];
                }
            }
            __syncthreads();

            // read A-frags (swizzled, conflict-free) + MFMA
            f32x4 accS0 = {0.f,0.f,0.f,0.f}, accS1 = {0.f,0.f,0.f,0.f};
            f32x4 accC0 = {0.f,0.f,0.f,0.f}, accC1 = {0.f,0.f,0.f,0.f};
            #pragma unroll
            for (int k = 0; k < 8; ++k) {
                const int roff = lr * 512 + (((k * 64) + lg * 16) ^ ((lr & 7) << 4));
                f16x8 aS = *(const f16x8*)(Sb + roff);
                f16x8 aC = *(const f16x8*)(Cb + roff);
                accS0 = __builtin_amdgcn_mfma_f32_16x16x32_f16(aS, Bf[0][k], accS0, 0, 0, 0);
                accC0 = __builtin_amdgcn_mfma_f32_16x16x32_f16(aC, Bf[0][k], accC0, 0, 0, 0);
                accS1 = __builtin_amdgcn_mfma_f32_16x16x32_f16(aS, Bf[1][k], accS1, 0, 0, 0);
                accC1 = __builtin_amdgcn_mfma_f32_16x16x32_f16(aC, Bf[1][k], accC1, 0, 0, 0);
            }

            // epilogue: dtheta = om + cc*(c*(Ks) - s*(Kc)); th = wrap(th + dt*dtheta)
            #pragma unroll
            for (int m = 0; m < 4; ++m) {
                th[0][m] = wrapf(th[0][m] + DTT * (om0 + cc * (cv[0][m] * accS0[m] - sv[0][m] * accC0[m])));
                th[1][m] = wrapf(th[1][m] + DTT * (om1 + cc * (cv[1][m] * accS1[m] - sv[1][m] * accC1[m])));
            }
        }
    }

    // ---- epilogue: theta out + coherence + decoder ----
    #pragma unroll
    for (int t = 0; t < 2; ++t) {
        const int i = (t == 0) ? iA : iB;
        #pragma unroll
        for (int m = 0; m < 4; ++m) {
            const int b = lg * 4 + m;
            th_lds[b * NOSC + i] = th[t][m];
            out_th[(size_t)(row0 + b) * NOSC + i] = th[t][m];
        }
    }

    // coherence: fresh (precise) sincos of final theta, reduce over i
    {
        float pS[4], pC[4];
        #pragma unroll
        for (int m = 0; m < 4; ++m) {
            float s0, c0, s1, c1;
            sincosf(th[0][m], &s0, &c0);
            sincosf(th[1][m], &s1, &c1);
            pS[m] = s0 + s1;
            pC[m] = c0 + c1;
        }
        #pragma unroll
        for (int m = 0; m < 4; ++m) {
            #pragma unroll
            for (int d = 1; d < 16; d <<= 1) {
                pS[m] += __shfl_xor(pS[m], d);
                pC[m] += __shfl_xor(pC[m], d);
            }
        }
        if (lr == 0) {
            #pragma unroll
            for (int m = 0; m < 4; ++m) {
                atomicAdd(&cohS[lg * 4 + m], pS[m]);
                atomicAdd(&cohC[lg * 4 + m], pC[m]);
            }
        }
    }
    __syncthreads();  // th_lds + coh sums visible

    if (tid < ROWS) {
        float ms = cohS[tid] * (1.0f / (float)NOSC);
        float mc = cohC[tid] * (1.0f / (float)NOSC);
        out_coh[row0 + tid] = sqrtf(ms * ms + mc * mc);
    }

    // decoder: b = tid>>5, lane handles 4 outputs; f32 vector
    {
        const int b  = tid >> 5;
        const int o0 = (tid & 31) * 4;
        float a0 = b_dec[o0], a1 = b_dec[o0 + 1], a2 = b_dec[o0 + 2], a3 = b_dec[o0 + 3];
        const float4* tr  = (const float4*)&th_lds[b * NOSC];
        const float4* wd0 = (const float4*)(W_dec + (size_t)(o0 + 0) * NOSC);
        const float4* wd1 = (const float4*)(W_dec + (size_t)(o0 + 1) * NOSC);
        const float4* wd2 = (const float4*)(W_dec + (size_t)(o0 + 2) * NOSC);
        const float4* wd3 = (const float4*)(W_dec + (size_t)(o0 + 3) * NOSC);
        #pragma unroll 4
        for (int k = 0; k < 64; ++k) {
            float4 t4 = tr[k];
            a0 += dot4(wd0[k], t4);
            a1 += dot4(wd1[k], t4);
            a2 += dot4(wd2[k], t4);
            a3 += dot4(wd3[k], t4);
        }
        float4 res = make_float4(a0, a1, a2, a3);
        *(float4*)&out_y[(size_t)(row0 + b) * NOUT + o0] = res;
    }
}

extern "C" void kernel_launch(void* const* d_in, const int* in_sizes, int n_in,
                              void* d_out, int out_size, void* d_ws, size_t ws_size,
                              hipStream_t stream) {
    helix_mfma<<<NB / ROWS, 512, 0, stream>>>(
        (const float*)d_in[0],  // x
        (const float*)d_in[1],  // W_enc
        (const float*)d_in[2],  // b_enc
        (const float*)d_in[3],  // Ks
        (const float*)d_in[4],  // omegas
        (const float*)d_in[5],  // K_globals
        (const float*)d_in[6],  // mu_gates
        (const float*)d_in[7],  // W_dec
        (const float*)d_in[8],  // b_dec
        (float*)d_out);
}

// Round 3
// 123.509 us; speedup vs baseline: 22.7935x; 1.5340x over previous
//
#include <hip/hip_runtime.h>

// Kuramoto helix network, fused persistent kernel, v3.
// Key ideas:
//  - [S;C] stacked in MFMA M-dim: A = [sin(8 rows); cos(8 rows)], B = K^T slice
//    -> one mfma_f32_16x16x32_f16 computes BOTH coupling GEMMs. 8 batch
//    rows/block -> grid 256 (all CUs busy).
//  - No sincos in the step loop: (s,c) state advanced by rotation with
//    poly sin/cos of the small dtheta (|dtheta|<~0.05). theta accumulates
//    unwrapped, wrapped once at the end.
//  - LDS A-buffer layout [kf 8][granule 64][16B], granule = row*4 +
//    (slice ^ (row>>2)): b128 reads are 64 distinct contiguous granules
//    (conflict-free); b16 writes spread across 16 banks.
//  - K cached in registers as f16 B-frags (64 VGPR/wave), reused 10 steps.

#define NB 2048
#define NIN 512
#define NOUT 128
#define NOSC 256
#define NL 4
#define NST 10
#define ROWS 8
#define DTT 0.1f

typedef _Float16 f16;
typedef _Float16 f16x8 __attribute__((ext_vector_type(8)));
typedef float f32x4 __attribute__((ext_vector_type(4)));

__device__ __forceinline__ float wrapf(float t) {
    return t - 6.28318530717958648f * rintf(t * 0.159154943091895336f);
}
__device__ __forceinline__ float dot4(float4 a, float4 b) {
    return a.x * b.x + a.y * b.y + a.z * b.z + a.w * b.w;
}

struct LaneCtx {
    float th[2][4], sv[2][4], cv[2][4];
    f16x8 Bf0[8], Bf1[8];
    float dtom0, dtom1, dtcc;
    bool  isS;
};

__device__ __forceinline__ void upd(float accm, float& th, float& s, float& c,
                                    float dtom, float dtcc, bool isS) {
    float oth = __shfl_xor(accm, 32);
    float aS = isS ? accm : oth;
    float aC = isS ? oth : accm;
    float diff = fmaf(c, aS, -(s * aC));
    float dth  = fmaf(diff, dtcc, dtom);
    th += dth;
    float q  = dth * dth;
    float sd = dth * fmaf(q, -0.166666667f, 1.0f);
    float cd = fmaf(q, fmaf(q, 0.0416666679f, -0.5f), 1.0f);
    float ns = fmaf(s, cd,  c * sd);
    float nc = fmaf(c, cd, -(s * sd));
    s = ns; c = nc;
}

__device__ __forceinline__ void step_body(int buf, char* smem, char* wA0, char* wA1,
                                          const char* rA, LaneCtx& L) {
    // write this lane's 8 values (S-half lanes write sin, C-half write cos)
    #pragma unroll
    for (int m = 0; m < 4; ++m) {
        *(f16*)(wA0 + buf * 8192 + m * 64) = (f16)(L.isS ? L.sv[0][m] : L.cv[0][m]);
        *(f16*)(wA1 + buf * 8192 + m * 64) = (f16)(L.isS ? L.sv[1][m] : L.cv[1][m]);
    }
    __syncthreads();
    f32x4 acc0 = {0.f, 0.f, 0.f, 0.f}, acc1 = {0.f, 0.f, 0.f, 0.f};
    #pragma unroll
    for (int kf = 0; kf < 8; ++kf) {
        f16x8 a = *(const f16x8*)(rA + buf * 8192 + kf * 1024);
        acc0 = __builtin_amdgcn_mfma_f32_16x16x32_f16(a, L.Bf0[kf], acc0, 0, 0, 0);
        acc1 = __builtin_amdgcn_mfma_f32_16x16x32_f16(a, L.Bf1[kf], acc1, 0, 0, 0);
    }
    #pragma unroll
    for (int m = 0; m < 4; ++m) {
        upd(acc0[m], L.th[0][m], L.sv[0][m], L.cv[0][m], L.dtom0, L.dtcc, L.isS);
        upd(acc1[m], L.th[1][m], L.sv[1][m], L.cv[1][m], L.dtom1, L.dtcc, L.isS);
    }
}

__global__ __launch_bounds__(512, 2) void helix3(
    const float* __restrict__ x,
    const float* __restrict__ W_enc,
    const float* __restrict__ b_enc,
    const float* __restrict__ Ks,
    const float* __restrict__ omegas,
    const float* __restrict__ Kgl,
    const float* __restrict__ mgl,
    const float* __restrict__ W_dec,
    const float* __restrict__ b_dec,
    float* __restrict__ out)
{
    // [0,16384): encoder x-stage (8x512 f32), then A double-buffer (2x8KB f16)
    // [16384,24576): th_lds f32[8][256]
    // [24576,25088): coherence partials [8 waves][8 rows] S then C
    __shared__ __align__(16) char smem[25088];
    float* th_lds = (float*)(smem + 16384);
    float* cohPS  = (float*)(smem + 24576);
    float* cohPC  = (float*)(smem + 24576 + 256);

    const int tid = threadIdx.x;
    const int w   = tid >> 6;
    const int ln  = tid & 63;
    const int lg  = ln >> 4;
    const int lr  = ln & 15;
    const int lr3 = lr >> 3, lr7 = lr & 7;
    const int rbase = (lg & 1) * 4;          // owned batch-row base
    const int c0 = 32 * w + lr, c1 = c0 + 16; // owned oscillator cols
    const int row0 = blockIdx.x * ROWS;

    float* out_y   = out;
    float* out_th  = out + (size_t)NB * NOUT;
    float* out_coh = out + (size_t)NB * (NOUT + NOSC);

    LaneCtx L;
    L.isS = (lg < 2);

    // ---- stage x rows (8x512 f32 = 16KB, flat copy) ----
    {
        const float4* xg = (const float4*)(x + (size_t)row0 * NIN);
        float4* xsv = (float4*)smem;
        xsv[tid]       = xg[tid];
        xsv[tid + 512] = xg[tid + 512];
    }
    __syncthreads();

    // ---- encoder: 512 threads cover 8 rows x 256 cols, 4 dots each ----
    {
        const int ec = 32 * w + (ln & 31);
        const int rg = ln >> 5;              // row group 0/1 -> rows rg*4+m
        const float* xrow = (const float*)smem + rg * 4 * NIN;
        const float4* wp  = (const float4*)(W_enc + (size_t)ec * NIN);
        float a0 = 0.f, a1 = 0.f, a2 = 0.f, a3 = 0.f;
        #pragma unroll 4
        for (int k = 0; k < 128; ++k) {
            float4 wv = wp[k];
            a0 += dot4(wv, *(const float4*)&xrow[0 * NIN + k * 4]);
            a1 += dot4(wv, *(const float4*)&xrow[1 * NIN + k * 4]);
            a2 += dot4(wv, *(const float4*)&xrow[2 * NIN + k * 4]);
            a3 += dot4(wv, *(const float4*)&xrow[3 * NIN + k * 4]);
        }
        float be = b_enc[ec];
        th_lds[(rg * 4 + 0) * NOSC + ec] = wrapf(a0 + be);
        th_lds[(rg * 4 + 1) * NOSC + ec] = wrapf(a1 + be);
        th_lds[(rg * 4 + 2) * NOSC + ec] = wrapf(a2 + be);
        th_lds[(rg * 4 + 3) * NOSC + ec] = wrapf(a3 + be);
    }
    __syncthreads();

    // ---- dynamics init: load owned theta (duplicated across lane-halves) ----
    #pragma unroll
    for (int m = 0; m < 4; ++m) {
        L.th[0][m] = th_lds[(rbase + m) * NOSC + c0];
        L.th[1][m] = th_lds[(rbase + m) * NOSC + c1];
    }
    #pragma unroll
    for (int t = 0; t < 2; ++t)
        #pragma unroll
        for (int m = 0; m < 4; ++m)
            sincosf(L.th[t][m], &L.sv[t][m], &L.cv[t][m]);

    // LDS addresses. Element (rowA, j) lives at byte:
    //   (j>>5)*1024 + [rowA*4 + (((j>>3)&3) ^ (rowA>>2))]*16 + (j&7)*2
    char* wA0 = smem + w * 1024 + lg * 256 + lr7 * 2 + ((lr3 ^ lg) * 16);
    char* wA1 = smem + w * 1024 + lg * 256 + lr7 * 2 + (((2 + lr3) ^ lg) * 16);
    const char* rA = smem + lr * 64 + ((lg ^ (lr >> 2)) * 16);

    // ---- 4 layers x 10 steps ----
    for (int l = 0; l < NL; ++l) {
        // B-frags: Bf[t][kf][e] = K[col_t][kf*32 + lg*8 + e], f16
        const float* KpA = Ks + (size_t)l * NOSC * NOSC + (size_t)c0 * NOSC;
        const float* KpB = KpA + 16 * NOSC;   // row c1
        #pragma unroll
        for (int kf = 0; kf < 8; ++kf) {
            const int j0 = kf * 32 + lg * 8;
            float4 a0 = *(const float4*)(KpA + j0);
            float4 a1 = *(const float4*)(KpA + j0 + 4);
            float4 b0 = *(const float4*)(KpB + j0);
            float4 b1 = *(const float4*)(KpB + j0 + 4);
            f16x8 fA, fB;
            fA[0]=(f16)a0.x; fA[1]=(f16)a0.y; fA[2]=(f16)a0.z; fA[3]=(f16)a0.w;
            fA[4]=(f16)a1.x; fA[5]=(f16)a1.y; fA[6]=(f16)a1.z; fA[7]=(f16)a1.w;
            fB[0]=(f16)b0.x; fB[1]=(f16)b0.y; fB[2]=(f16)b0.z; fB[3]=(f16)b0.w;
            fB[4]=(f16)b1.x; fB[5]=(f16)b1.y; fB[6]=(f16)b1.z; fB[7]=(f16)b1.w;
            L.Bf0[kf] = fA;
            L.Bf1[kf] = fB;
        }
        const float cc = Kgl[l] * (1.0f / (float)NOSC) * (mgl[l] * 0.5f);
        L.dtcc  = DTT * cc;
        L.dtom0 = DTT * omegas[l * NOSC + c0];
        L.dtom1 = DTT * omegas[l * NOSC + c1];

        #pragma unroll 1
        for (int p = 0; p < NST / 2; ++p) {
            step_body(0, smem, wA0, wA1, rA, L);
            step_body(1, smem, wA0, wA1, rA, L);
        }
    }

    // ---- wrap final theta; write theta out + stage for decoder ----
    float wth[2][4];
    #pragma unroll
    for (int t = 0; t < 2; ++t)
        #pragma unroll
        for (int m = 0; m < 4; ++m)
            wth[t][m] = wrapf(L.th[t][m]);

    if (L.isS) {
        #pragma unroll
        for (int m = 0; m < 4; ++m) {
            out_th[(size_t)(row0 + rbase + m) * NOSC + c0] = wth[0][m];
            out_th[(size_t)(row0 + rbase + m) * NOSC + c1] = wth[1][m];
            th_lds[(rbase + m) * NOSC + c0] = wth[0][m];
            th_lds[(rbase + m) * NOSC + c1] = wth[1][m];
        }
    }

    // ---- coherence partials (dup half zeroed to avoid double count) ----
    {
        float pS[4], pC[4];
        #pragma unroll
        for (int m = 0; m < 4; ++m) {
            float s0, cs0, s1, cs1;
            sincosf(wth[0][m], &s0, &cs0);
            sincosf(wth[1][m], &s1, &cs1);
            pS[m] = L.isS ? (s0 + s1) : 0.f;
            pC[m] = L.isS ? (cs0 + cs1) : 0.f;
        }
        #pragma unroll
        for (int m = 0; m < 4; ++m) {
            #pragma unroll
            for (int d = 1; d <= 32; d <<= 1) {   // 1,2,4,8,16,32 (16 merges dup lr copies? no: lr<16 tree + lg pair)
                pS[m] += __shfl_xor(pS[m], d);
                pC[m] += __shfl_xor(pC[m], d);
            }
        }
        // after full 64-lane reduce, every lane has sum over the wave's
        // 32 cols (dup-half contributed zeros) for row rbase+m of its lg&1.
        // lanes with lg=0 hold rows 0..3 sums?? No: reduce mixed lg groups.
        // Fix: the d=16 exchange mixes lg0<->lg1 (different rows)!
        // -> use explicit mask set {1,2,4,8,32} only.
    }
    // correct coherence reduce: lr-tree (1,2,4,8) + dup-pair (32) only
    {
        float pS[4], pC[4];
        #pragma unroll
        for (int m = 0; m < 4; ++m) {
            float s0, cs0, s1, cs1;
            sincosf(wth[0][m], &s0, &cs0);
            sincosf(wth[1][m], &s1, &cs1);
            pS[m] = L.isS ? (s0 + s1) : 0.f;
            pC[m] = L.isS ? (cs0 + cs1) : 0.f;
        }
        #pragma unroll
        for (int m = 0; m < 4; ++m) {
            pS[m] += __shfl_xor(pS[m], 1);  pC[m] += __shfl_xor(pC[m], 1);
            pS[m] += __shfl_xor(pS[m], 2);  pC[m] += __shfl_xor(pC[m], 2);
            pS[m] += __shfl_xor(pS[m], 4);  pC[m] += __shfl_xor(pC[m], 4);
            pS[m] += __shfl_xor(pS[m], 8);  pC[m] += __shfl_xor(pC[m], 8);
            pS[m] += __shfl_xor(pS[m], 32); pC[m] += __shfl_xor(pC[m], 32);
        }
        if (lr == 0 && L.isS) {
            #pragma unroll
            for (int m = 0; m < 4; ++m) {
                cohPS[w * 8 + rbase + m] = pS[m];
                cohPC[w * 8 + rbase + m] = pC[m];
            }
        }
    }
    __syncthreads();

    if (tid < ROWS) {
        float ssum = 0.f, csum = 0.f;
        #pragma unroll
        for (int wv = 0; wv < 8; ++wv) {
            ssum += cohPS[wv * 8 + tid];
            csum += cohPC[wv * 8 + tid];
        }
        float ms = ssum * (1.0f / (float)NOSC);
        float mc = csum * (1.0f / (float)NOSC);
        out_coh[row0 + tid] = sqrtf(ms * ms + mc * mc);
    }

    // ---- decoder: wave w handles batch row w; lane -> 2 outputs ----
    {
        const int o0 = ln * 2;
        float a0 = b_dec[o0], a1 = b_dec[o0 + 1];
        const float4* tr  = (const float4*)&th_lds[w * NOSC];
        const float4* wd0 = (const float4*)(W_dec + (size_t)o0 * NOSC);
        const float4* wd1 = (const float4*)(W_dec + (size_t)(o0 + 1) * NOSC);
        #pragma unroll 4
        for (int k = 0; k < 64; ++k) {
            float4 t4 = tr[k];
            a0 += dot4(wd0[k], t4);
            a1 += dot4(wd1[k], t4);
        }
        *(float2*)&out_y[(size_t)(row0 + w) * NOUT + o0] = make_float2(a0, a1);
    }
}

extern "C" void kernel_launch(void* const* d_in, const int* in_sizes, int n_in,
                              void* d_out, int out_size, void* d_ws, size_t ws_size,
                              hipStream_t stream) {
    helix3<<<NB / ROWS, 512, 0, stream>>>(
        (const float*)d_in[0],  // x
        (const float*)d_in[1],  // W_enc
        (const float*)d_in[2],  // b_enc
        (const float*)d_in[3],  // Ks
        (const float*)d_in[4],  // omegas
        (const float*)d_in[5],  // K_globals
        (const float*)d_in[6],  // mu_gates
        (const float*)d_in[7],  // W_dec
        (const float*)d_in[8],  // b_dec
        (float*)d_out);
}

// Round 4
// 112.080 us; speedup vs baseline: 25.1177x; 1.1020x over previous
//
#include <hip/hip_runtime.h>

// Kuramoto helix network, fused persistent kernel, v5.
// vs v3: interleaved M-stack A = [S r0, C r0, S r1, C r1, ...]:
//   D rows 4*lg+reg => lane group lg holds (accS,accC,accS,accC) for batch
//   rows 2lg, 2lg+1 IN-REGISTER -> no shuffle, no duplicated upd work.
// LDS A layout [j-granule 32][m 16][16B]: b128 A-frag reads are contiguous
// (conflict-free); 8x b16 writes ~4-way (cheap).
// K cached in registers as f16 B-frags; (s,c) advanced by small-angle
// rotation (no sincos in loop); theta accumulates unwrapped, wrapped once.

#define NB 2048
#define NIN 512
#define NOUT 128
#define NOSC 256
#define NL 4
#define NST 10
#define ROWS 8
#define DTT 0.1f

typedef _Float16 f16;
typedef _Float16 f16x8 __attribute__((ext_vector_type(8)));
typedef float f32x4 __attribute__((ext_vector_type(4)));

__device__ __forceinline__ float wrapf(float t) {
    return t - 6.28318530717958648f * rintf(t * 0.159154943091895336f);
}
__device__ __forceinline__ float dot4a(float4 a, float4 b, float acc) {
    return fmaf(a.x, b.x, fmaf(a.y, b.y, fmaf(a.z, b.z, fmaf(a.w, b.w, acc))));
}

struct St {
    float th[2][2], s[2][2], c[2][2];   // [tile t][row-pair p]
};

__device__ __forceinline__ void upd1(float aS, float aC, float dtom, float dtcc,
                                     float& th, float& s, float& c) {
    float diff = fmaf(c, aS, -(s * aC));
    float dth  = fmaf(diff, dtcc, dtom);
    th += dth;
    float q  = dth * dth;
    float sd = dth * fmaf(q, -0.166666667f, 1.0f);
    float cd = fmaf(q, fmaf(q, 0.0416666679f, -0.5f), 1.0f);
    float ns = fmaf(s, cd,  c * sd);
    float nc = fmaf(c, cd, -(s * sd));
    s = ns; c = nc;
}

__device__ __forceinline__ void step_body(char* Sb, int wb0, int wb1, int rb,
    const f16x8* Bf0, const f16x8* Bf1,
    float dtom0, float dtom1, float dtcc, St& L)
{
    // write 8 f16: value (m = 4lg+2p+sc, col c0/c1); consecutive 16B granules
    #pragma unroll
    for (int p = 0; p < 2; ++p) {
        *(f16*)(Sb + wb0 + (2*p+0)*16) = (f16)L.s[0][p];
        *(f16*)(Sb + wb0 + (2*p+1)*16) = (f16)L.c[0][p];
        *(f16*)(Sb + wb1 + (2*p+0)*16) = (f16)L.s[1][p];
        *(f16*)(Sb + wb1 + (2*p+1)*16) = (f16)L.c[1][p];
    }
    __syncthreads();
    f32x4 acc0 = {0.f,0.f,0.f,0.f}, acc1 = {0.f,0.f,0.f,0.f};
    #pragma unroll
    for (int kf = 0; kf < 8; ++kf) {
        f16x8 a = *(const f16x8*)(Sb + rb + kf * 1024);
        acc0 = __builtin_amdgcn_mfma_f32_16x16x32_f16(a, Bf0[kf], acc0, 0, 0, 0);
        acc1 = __builtin_amdgcn_mfma_f32_16x16x32_f16(a, Bf1[kf], acc1, 0, 0, 0);
    }
    #pragma unroll
    for (int p = 0; p < 2; ++p) {
        upd1(acc0[2*p], acc0[2*p+1], dtom0, dtcc, L.th[0][p], L.s[0][p], L.c[0][p]);
        upd1(acc1[2*p], acc1[2*p+1], dtom1, dtcc, L.th[1][p], L.s[1][p], L.c[1][p]);
    }
}

__global__ __launch_bounds__(512, 2) void helix5(
    const float* __restrict__ x,
    const float* __restrict__ W_enc,
    const float* __restrict__ b_enc,
    const float* __restrict__ Ks,
    const float* __restrict__ omegas,
    const float* __restrict__ Kgl,
    const float* __restrict__ mgl,
    const float* __restrict__ W_dec,
    const float* __restrict__ b_dec,
    float* __restrict__ out)
{
    // [0,16384): encoder x-stage (8x512 f32) -> A dbuf (2 x 8KB f16)
    // [16384,24576): th_lds f32[8][256]
    // [24576,25088): coherence partials [8 waves][8 rows] S then C
    __shared__ __align__(16) char smem[25088];
    float* th_lds = (float*)(smem + 16384);
    float* cohPS  = (float*)(smem + 24576);
    float* cohPC  = (float*)(smem + 24576 + 256);

    const int tid = threadIdx.x;
    const int w   = tid >> 6;
    const int ln  = tid & 63;
    const int lg  = ln >> 4;
    const int lr  = ln & 15;
    const int r0  = 2 * lg;            // lane's batch rows r0, r0+1
    const int c0  = 32 * w + lr;       // lane's oscillator cols c0, c1
    const int c1  = c0 + 16;
    const int row0 = blockIdx.x * ROWS;

    float* out_y   = out;
    float* out_th  = out + (size_t)NB * NOUT;
    float* out_coh = out + (size_t)NB * (NOUT + NOSC);

    // ---- stage x rows (8x512 f32 = 16KB) ----
    {
        const float4* xg = (const float4*)(x + (size_t)row0 * NIN);
        float4* xsv = (float4*)smem;
        xsv[tid]       = xg[tid];
        xsv[tid + 512] = xg[tid + 512];
    }
    __syncthreads();

    // ---- encoder: thread -> col ec, 4 rows; x reads are broadcasts ----
    {
        const int ec = 32 * w + (ln & 31);
        const int rg = ln >> 5;
        const float* xrow = (const float*)smem + rg * 4 * NIN;
        const float4* wp  = (const float4*)(W_enc + (size_t)ec * NIN);
        float a0 = 0.f, a1 = 0.f, a2 = 0.f, a3 = 0.f;
        #pragma unroll 4
        for (int k = 0; k < 128; ++k) {
            float4 wv = wp[k];
            a0 = dot4a(wv, *(const float4*)&xrow[0 * NIN + k * 4], a0);
            a1 = dot4a(wv, *(const float4*)&xrow[1 * NIN + k * 4], a1);
            a2 = dot4a(wv, *(const float4*)&xrow[2 * NIN + k * 4], a2);
            a3 = dot4a(wv, *(const float4*)&xrow[3 * NIN + k * 4], a3);
        }
        float be = b_enc[ec];
        th_lds[(rg * 4 + 0) * NOSC + ec] = wrapf(a0 + be);
        th_lds[(rg * 4 + 1) * NOSC + ec] = wrapf(a1 + be);
        th_lds[(rg * 4 + 2) * NOSC + ec] = wrapf(a2 + be);
        th_lds[(rg * 4 + 3) * NOSC + ec] = wrapf(a3 + be);
    }
    __syncthreads();   // xs reads + th_lds writes complete

    // ---- dynamics init ----
    St L;
    #pragma unroll
    for (int p = 0; p < 2; ++p) {
        L.th[0][p] = th_lds[(r0 + p) * NOSC + c0];
        L.th[1][p] = th_lds[(r0 + p) * NOSC + c1];
    }
    #pragma unroll
    for (int t = 0; t < 2; ++t)
        #pragma unroll
        for (int p = 0; p < 2; ++p)
            sincosf(L.th[t][p], &L.s[t][p], &L.c[t][p]);

    // A element (m, j) at byte (j>>3)*256 + m*16 + (j&7)*2  (granule [jf][m])
    const int wb0 = ((c0 >> 3) << 8) | ((c0 & 7) << 1) | (lg << 6);
    const int wb1 = wb0 + 512;                       // c1 = c0+16 -> jf+2
    const int rb  = lg * 256 + lr * 16;              // + kf*1024

    // ---- 4 layers x 10 steps ----
    for (int l = 0; l < NL; ++l) {
        f16x8 Bf0[8], Bf1[8];
        const float* KpA = Ks + (size_t)l * NOSC * NOSC + (size_t)c0 * NOSC;
        const float* KpB = KpA + 16 * NOSC;
        #pragma unroll
        for (int kf = 0; kf < 8; ++kf) {
            const int j0 = kf * 32 + lg * 8;
            float4 a0 = *(const float4*)(KpA + j0);
            float4 a1 = *(const float4*)(KpA + j0 + 4);
            float4 b0 = *(const float4*)(KpB + j0);
            float4 b1 = *(const float4*)(KpB + j0 + 4);
            f16x8 fA, fB;
            fA[0]=(f16)a0.x; fA[1]=(f16)a0.y; fA[2]=(f16)a0.z; fA[3]=(f16)a0.w;
            fA[4]=(f16)a1.x; fA[5]=(f16)a1.y; fA[6]=(f16)a1.z; fA[7]=(f16)a1.w;
            fB[0]=(f16)b0.x; fB[1]=(f16)b0.y; fB[2]=(f16)b0.z; fB[3]=(f16)b0.w;
            fB[4]=(f16)b1.x; fB[5]=(f16)b1.y; fB[6]=(f16)b1.z; fB[7]=(f16)b1.w;
            Bf0[kf] = fA;
            Bf1[kf] = fB;
        }
        const float cc    = Kgl[l] * (1.0f / (float)NOSC) * (mgl[l] * 0.5f);
        const float dtcc  = DTT * cc;
        const float dtom0 = DTT * omegas[l * NOSC + c0];
        const float dtom1 = DTT * omegas[l * NOSC + c1];

        #pragma unroll 1
        for (int p5 = 0; p5 < NST / 2; ++p5) {
            step_body(smem,        wb0, wb1, rb, Bf0, Bf1, dtom0, dtom1, dtcc, L);
            step_body(smem + 8192, wb0, wb1, rb, Bf0, Bf1, dtom0, dtom1, dtcc, L);
        }
    }

    // ---- epilogue ----
    // wrap + stage final theta; coherence partials from in-register (s,c)
    #pragma unroll
    for (int p = 0; p < 2; ++p) {
        float w0 = wrapf(L.th[0][p]);
        float w1 = wrapf(L.th[1][p]);
        th_lds[(r0 + p) * NOSC + c0] = w0;
        th_lds[(r0 + p) * NOSC + c1] = w1;
        float ps = L.s[0][p] + L.s[1][p];
        float pc = L.c[0][p] + L.c[1][p];
        ps += __shfl_xor(ps, 1);  pc += __shfl_xor(pc, 1);
        ps += __shfl_xor(ps, 2);  pc += __shfl_xor(pc, 2);
        ps += __shfl_xor(ps, 4);  pc += __shfl_xor(pc, 4);
        ps += __shfl_xor(ps, 8);  pc += __shfl_xor(pc, 8);
        if (lr == 0) {
            cohPS[w * 8 + r0 + p] = ps;
            cohPC[w * 8 + r0 + p] = pc;
        }
    }
    __syncthreads();

    // theta out, coalesced: wave w writes row w
    {
        const float4* src = (const float4*)&th_lds[w * NOSC];
        float4 v = src[ln];
        *(float4*)&out_th[(size_t)(row0 + w) * NOSC + ln * 4] = v;
    }

    if (tid < ROWS) {
        float ss = 0.f, cs = 0.f;
        #pragma unroll
        for (int wv = 0; wv < 8; ++wv) {
            ss += cohPS[wv * 8 + tid];
            cs += cohPC[wv * 8 + tid];
        }
        float ms = ss * (1.0f / (float)NOSC);
        float mc = cs * (1.0f / (float)NOSC);
        out_coh[row0 + tid] = sqrtf(ms * ms + mc * mc);
    }

    // decoder: wave w -> batch row w; lane -> 2 outputs
    {
        const int o0 = ln * 2;
        float a0 = b_dec[o0], a1 = b_dec[o0 + 1];
        const float4* tr  = (const float4*)&th_lds[w * NOSC];
        const float4* wd0 = (const float4*)(W_dec + (size_t)o0 * NOSC);
        const float4* wd1 = (const float4*)(W_dec + (size_t)(o0 + 1) * NOSC);
        #pragma unroll 4
        for (int k = 0; k < 64; ++k) {
            float4 t4 = tr[k];
            a0 = dot4a(wd0[k], t4, a0);
            a1 = dot4a(wd1[k], t4, a1);
        }
        *(float2*)&out_y[(size_t)(row0 + w) * NOUT + o0] = make_float2(a0, a1);
    }
}

extern "C" void kernel_launch(void* const* d_in, const int* in_sizes, int n_in,
                              void* d_out, int out_size, void* d_ws, size_t ws_size,
                              hipStream_t stream) {
    helix5<<<NB / ROWS, 512, 0, stream>>>(
        (const float*)d_in[0],  // x
        (const float*)d_in[1],  // W_enc
        (const float*)d_in[2],  // b_enc
        (const float*)d_in[3],  // Ks
        (const float*)d_in[4],  // omegas
        (const float*)d_in[5],  // K_globals
        (const float*)d_in[6],  // mu_gates
        (const float*)d_in[7],  // W_dec
        (const float*)d_in[8],  // b_dec
        (float*)d_out);
}

// Round 5
// 73.387 us; speedup vs baseline: 38.3611x; 1.5273x over previous
//
#include <hip/hip_runtime.h>

// Kuramoto helix network v6: 512 blocks x 256 thr x 4 rows (2 blocks/CU ->
// two independent barrier domains per CU), MFMA encoder (f16 hi/lo split =
// f32-class accuracy) + MFMA decoder, prep kernel pre-lays K/W_enc/W_dec in
// f16 fragment layout in d_ws (coalesced dwordx4 loads, no cvt VALU).
// Dynamics: A=[S r,C r interleaved](8 rows)+zeros, K in regs (128 VGPR),
// (s,c) advanced by small-angle rotation, one barrier/step, LDS dbuf.

#define NB 2048
#define NIN 512
#define NOUT 128
#define NOSC 256
#define DTT 0.1f

#define WS_WENC (512*1024)
#define WS_WD   (1024*1024)

typedef _Float16 f16;
typedef _Float16 f16x8 __attribute__((ext_vector_type(8)));
typedef float f32x4 __attribute__((ext_vector_type(4)));

__device__ __forceinline__ float wrapf(float t) {
    return t - 6.28318530717958648f * rintf(t * 0.159154943091895336f);
}

__device__ __forceinline__ void upd1(float aS, float aC, float dtom, float dtcc,
                                     float& th, float& s, float& c) {
    float diff = fmaf(c, aS, -(s * aC));
    float dth  = fmaf(diff, dtcc, dtom);
    th += dth;
    float q  = dth * dth;
    float sd = dth * fmaf(q, -0.166666667f, 1.0f);
    float cd = fmaf(q, fmaf(q, 0.0416666679f, -0.5f), 1.0f);
    float ns = fmaf(s, cd,  c * sd);
    float nc = fmaf(c, cd, -(s * sd));
    s = ns; c = nc;
}

// ---- prep: lay K (f16), W_enc (f16 hi/lo), W_dec (f16) out in frag layout ----
// granule (16B) = 8 f16 consumed by lane ln=(lg,lr) of one MFMA fragment.
__global__ __launch_bounds__(256) void helix_prep(
    const float* __restrict__ Ks, const float* __restrict__ Wenc,
    const float* __restrict__ Wdec, char* __restrict__ ws)
{
    const int g = blockIdx.x * 256 + threadIdx.x;
    if (g < 32768) {                       // K: [l 4][nt 16][kf 8][ln 64]
        const int ln = g & 63, lg = ln >> 4, lr = ln & 15;
        const int kf = (g >> 6) & 7, nt = (g >> 9) & 15, l = (g >> 13) & 3;
        const float* s = Ks + (((size_t)l * NOSC + nt * 16 + lr) * NOSC + kf * 32 + lg * 8);
        f16x8 o;
        #pragma unroll
        for (int e = 0; e < 8; ++e) o[e] = (f16)s[e];
        *(f16x8*)(ws + (size_t)g * 16) = o;
    } else if (g < 65536) {                // Wenc: [nt 16][kf 16][h 2][ln 64]
        const int q = g - 32768;
        const int ln = q & 63, lg = ln >> 4, lr = ln & 15;
        const int h = (q >> 6) & 1, kf = (q >> 7) & 15, nt = (q >> 11) & 15;
        const float* s = Wenc + ((size_t)(nt * 16 + lr) * NIN + kf * 32 + lg * 8);
        f16x8 o;
        #pragma unroll
        for (int e = 0; e < 8; ++e) {
            float v = s[e];
            f16 hi = (f16)v;
            o[e] = h ? (f16)(v - (float)hi) : hi;
        }
        *(f16x8*)(ws + WS_WENC + (size_t)q * 16) = o;
    } else if (g < 69632) {                // Wdec: [nt 8][kf 8][ln 64]
        const int q = g - 65536;
        const int ln = q & 63, lg = ln >> 4, lr = ln & 15;
        const int kf = (q >> 6) & 7, nt = (q >> 9) & 7;
        const float* s = Wdec + ((size_t)(nt * 16 + lr) * NOSC + kf * 32 + lg * 8);
        f16x8 o;
        #pragma unroll
        for (int e = 0; e < 8; ++e) o[e] = (f16)s[e];
        *(f16x8*)(ws + WS_WD + (size_t)q * 16) = o;
    }
}

__global__ __launch_bounds__(256, 2) void helix6(
    const float* __restrict__ x,
    const float* __restrict__ b_enc,
    const float* __restrict__ omegas,
    const float* __restrict__ Kgl,
    const float* __restrict__ mgl,
    const float* __restrict__ b_dec,
    const char* __restrict__ ws,
    float* __restrict__ out)
{
    // [0,16384): encoder A (16x512 f16) -> dynamics dbuf (2x8KB) -> decoder A
    // [16384,20480): th_lds f32[4][256]
    // [20480,20608): coherence partials [wv 4][r 4][2]
    __shared__ __align__(16) char smem[20736];
    float* th_lds = (float*)(smem + 16384);
    float* coh    = (float*)(smem + 20480);

    const int tid = threadIdx.x;
    const int wv = tid >> 6, ln = tid & 63, lg = ln >> 4, lr = ln & 15;
    const int row0 = blockIdx.x * 4;

    float* out_y   = out;
    float* out_th  = out + (size_t)NB * NOUT;
    float* out_coh = out + (size_t)NB * (NOUT + NOSC);

    const int4 zz = make_int4(0, 0, 0, 0);

    // ---- P0: x -> encoder-A LDS (hi rows 0-3, lo rows 4-7, zeros 8-15) ----
    {
        const int k0 = (ln) * 8;                 // wv==tid>>6 is the row
        const float* xp = x + (size_t)(row0 + wv) * NIN + k0;
        float4 v0 = *(const float4*)xp;
        float4 v1 = *(const float4*)(xp + 4);
        float vv[8] = {v0.x, v0.y, v0.z, v0.w, v1.x, v1.y, v1.z, v1.w};
        f16x8 hi, lo;
        #pragma unroll
        for (int e = 0; e < 8; ++e) {
            hi[e] = (f16)vv[e];
            lo[e] = (f16)(vv[e] - (float)hi[e]);
        }
        char* base = smem + (k0 >> 3) * 256;
        *(f16x8*)(base + wv * 16)        = hi;
        *(f16x8*)(base + (wv + 4) * 16)  = lo;
        *(int4*)(base + (wv + 8) * 16)   = zz;
        *(int4*)(base + (wv + 12) * 16)  = zz;
    }
    __syncthreads();

    // ---- P1: encoder MFMA ----
    float th[4][2], sv[4][2], cv[4][2];
    {
        f32x4 accH[4] = {{0,0,0,0},{0,0,0,0},{0,0,0,0},{0,0,0,0}};
        f32x4 accL[4] = {{0,0,0,0},{0,0,0,0},{0,0,0,0},{0,0,0,0}};
        const char* aBase = smem + lg * 256 + lr * 16;
        const char* wE0 = ws + WS_WENC + (size_t)(4 * wv + 0) * 32768 + ln * 16;
        const char* wE1 = wE0 + 32768, *wE2 = wE0 + 65536, *wE3 = wE0 + 98304;
        const char* wE[4] = {wE0, wE1, wE2, wE3};
        #pragma unroll 4
        for (int kf = 0; kf < 16; ++kf) {
            f16x8 a = *(const f16x8*)(aBase + kf * 1024);
            #pragma unroll
            for (int t = 0; t < 4; ++t) {
                f16x8 bh = *(const f16x8*)(wE[t] + kf * 2048);
                f16x8 bl = *(const f16x8*)(wE[t] + kf * 2048 + 1024);
                accH[t] = __builtin_amdgcn_mfma_f32_16x16x32_f16(a, bh, accH[t], 0, 0, 0);
                accL[t] = __builtin_amdgcn_mfma_f32_16x16x32_f16(a, bl, accL[t], 0, 0, 0);
            }
        }
        #pragma unroll
        for (int t = 0; t < 4; ++t) {
            const int ct = 64 * wv + 16 * t + lr;
            const float be = b_enc[ct];
            float tp[4];
            #pragma unroll
            for (int e = 0; e < 4; ++e) {
                float v = accH[t][e] + accL[t][e];
                v += __shfl_xor(v, 16);
                tp[e] = v;
            }
            #pragma unroll
            for (int p = 0; p < 2; ++p) {
                th[t][p] = wrapf(tp[(2 * lg + p) & 3] + be);
                sincosf(th[t][p], &sv[t][p], &cv[t][p]);
            }
        }
    }
    __syncthreads();

    // ---- P2: zero dynamics-A rows 8..15 in both buffers ----
    #pragma unroll
    for (int q = 0; q < 2; ++q) {
        const int id = tid + q * 256;
        *(int4*)(smem + (id >> 8) * 8192 + ((id & 255) >> 3) * 256 + (8 + (id & 7)) * 16) = zz;
    }
    __syncthreads();

    // ---- dynamics ----
    int wb[4];
    #pragma unroll
    for (int t = 0; t < 4; ++t)
        wb[t] = (8 * wv + 2 * t + (lr >> 3)) * 256 + lg * 64 + (lr & 7) * 2;
    const int rb = lg * 256 + lr * 16;

    f16x8 Bf[4][8];
    float dtom[4], dtcc;

    auto STEP = [&](char* Sb) {
        if (lg < 2) {
            #pragma unroll
            for (int t = 0; t < 4; ++t)
                #pragma unroll
                for (int p = 0; p < 2; ++p) {
                    *(f16*)(Sb + wb[t] + (2 * p + 0) * 16) = (f16)sv[t][p];
                    *(f16*)(Sb + wb[t] + (2 * p + 1) * 16) = (f16)cv[t][p];
                }
        }
        __syncthreads();
        f32x4 acc[4] = {{0,0,0,0},{0,0,0,0},{0,0,0,0},{0,0,0,0}};
        #pragma unroll
        for (int kf = 0; kf < 8; ++kf) {
            f16x8 a = *(const f16x8*)(Sb + kf * 1024 + rb);
            #pragma unroll
            for (int t = 0; t < 4; ++t)
                acc[t] = __builtin_amdgcn_mfma_f32_16x16x32_f16(a, Bf[t][kf], acc[t], 0, 0, 0);
        }
        #pragma unroll
        for (int t = 0; t < 4; ++t)
            #pragma unroll
            for (int p = 0; p < 2; ++p)
                upd1(acc[t][2 * p], acc[t][2 * p + 1], dtom[t], dtcc,
                     th[t][p], sv[t][p], cv[t][p]);
    };

    for (int l = 0; l < 4; ++l) {
        #pragma unroll
        for (int t = 0; t < 4; ++t) {
            const char* kb = ws + (size_t)l * 131072 + (size_t)(4 * wv + t) * 8192 + ln * 16;
            #pragma unroll
            for (int kf = 0; kf < 8; ++kf)
                Bf[t][kf] = *(const f16x8*)(kb + kf * 1024);
        }
        dtcc = DTT * Kgl[l] * (1.0f / (float)NOSC) * (mgl[l] * 0.5f);
        #pragma unroll
        for (int t = 0; t < 4; ++t)
            dtom[t] = DTT * omegas[l * NOSC + 64 * wv + 16 * t + lr];

        #pragma unroll 1
        for (int p5 = 0; p5 < 5; ++p5) {
            STEP(smem);
            STEP(smem + 8192);
        }
    }

    // ---- epilogue ----
    // wrap; stage th (f32 for out, f16 decoder-A rows 0-3); coherence partials
    if (lg < 2) {
        #pragma unroll
        for (int t = 0; t < 4; ++t)
            #pragma unroll
            for (int p = 0; p < 2; ++p) {
                const int ct = 64 * wv + 16 * t + lr;
                const int r = 2 * lg + p;
                const float wt = wrapf(th[t][p]);
                th_lds[r * NOSC + ct] = wt;
                *(f16*)(smem + (ct >> 3) * 256 + r * 16 + (lr & 7) * 2) = (f16)wt;
            }
    }
    if (tid < 128)   // zero decoder-A rows 4-7 (8-15 still zero from P2)
        *(int4*)(smem + (tid >> 2) * 256 + (4 + (tid & 3)) * 16) = zz;
    #pragma unroll
    for (int p = 0; p < 2; ++p) {
        float pS = sv[0][p] + sv[1][p] + sv[2][p] + sv[3][p];
        float pC = cv[0][p] + cv[1][p] + cv[2][p] + cv[3][p];
        pS += __shfl_xor(pS, 1); pC += __shfl_xor(pC, 1);
        pS += __shfl_xor(pS, 2); pC += __shfl_xor(pC, 2);
        pS += __shfl_xor(pS, 4); pC += __shfl_xor(pC, 4);
        pS += __shfl_xor(pS, 8); pC += __shfl_xor(pC, 8);
        if (lr == 0 && lg < 2) {
            coh[(wv * 4 + 2 * lg + p) * 2]     = pS;
            coh[(wv * 4 + 2 * lg + p) * 2 + 1] = pC;
        }
    }
    __syncthreads();

    // theta out (coalesced, rows row0..row0+3 contiguous)
    {
        float4 v = *(float4*)(th_lds + tid * 4);
        *(float4*)(out_th + (size_t)row0 * NOSC + tid * 4) = v;
    }
    // coherence
    if (tid < 4) {
        float S = 0.f, C = 0.f;
        #pragma unroll
        for (int w2 = 0; w2 < 4; ++w2) {
            S += coh[(w2 * 4 + tid) * 2];
            C += coh[(w2 * 4 + tid) * 2 + 1];
        }
        S *= (1.0f / (float)NOSC);
        C *= (1.0f / (float)NOSC);
        out_coh[row0 + tid] = sqrtf(S * S + C * C);
    }
    // decoder MFMA: wave wv -> out cols [32wv, 32wv+32)
    {
        f32x4 aD[2] = {{0,0,0,0},{0,0,0,0}};
        #pragma unroll
        for (int kf = 0; kf < 8; ++kf) {
            f16x8 a = *(const f16x8*)(smem + kf * 1024 + rb);
            #pragma unroll
            for (int u = 0; u < 2; ++u) {
                f16x8 bw = *(const f16x8*)(ws + WS_WD + (size_t)(2 * wv + u) * 8192 + kf * 1024 + ln * 16);
                aD[u] = __builtin_amdgcn_mfma_f32_16x16x32_f16(a, bw, aD[u], 0, 0, 0);
            }
        }
        if (lg == 0) {
            #pragma unroll
            for (int u = 0; u < 2; ++u) {
                const int col = (2 * wv + u) * 16 + lr;
                const float bd = b_dec[col];
                #pragma unroll
                for (int e = 0; e < 4; ++e)
                    out_y[(size_t)(row0 + e) * NOUT + col] = aD[u][e] + bd;
            }
        }
    }
}

extern "C" void kernel_launch(void* const* d_in, const int* in_sizes, int n_in,
                              void* d_out, int out_size, void* d_ws, size_t ws_size,
                              hipStream_t stream) {
    const float* x     = (const float*)d_in[0];
    const float* W_enc = (const float*)d_in[1];
    const float* b_enc = (const float*)d_in[2];
    const float* Ks    = (const float*)d_in[3];
    const float* omg   = (const float*)d_in[4];
    const float* Kgl   = (const float*)d_in[5];
    const float* mgl   = (const float*)d_in[6];
    const float* W_dec = (const float*)d_in[7];
    const float* b_dec = (const float*)d_in[8];
    char* ws = (char*)d_ws;

    helix_prep<<<272, 256, 0, stream>>>(Ks, W_enc, W_dec, ws);
    helix6<<<NB / 4, 256, 0, stream>>>(x, b_enc, omg, Kgl, mgl, b_dec, ws, (float*)d_out);
}